// Round 18
// baseline (312.052 us; speedup 1.0000x reference)
//
#include <hip/hip_runtime.h>
#include <hip/hip_bf16.h>
#include <hip/hip_fp16.h>
#include <cstddef>

// Problem constants
constexpr int B_  = 2;
constexpr int T_  = 8;
constexpr int HW_ = 37;          // H == W == 37
constexpr int N_  = HW_ * HW_;   // 1369
constexpr int C_  = 384;
constexpr int NH_ = 8;
constexpr int MP_ = 8;
constexpr int HD_ = C_ / NH_;    // 48
constexpr int M_  = B_ * T_ * N_; // 21904

typedef short bf16x8 __attribute__((ext_vector_type(8)));
typedef float f32x4 __attribute__((ext_vector_type(4)));
typedef _Float16 h16x2 __attribute__((ext_vector_type(2)));
typedef unsigned u32x3 __attribute__((ext_vector_type(3)));
typedef u32x3 uau32x3 __attribute__((aligned(4)));

static __device__ __forceinline__ unsigned short bf16_bits(float v) {
  __hip_bfloat16 b = __float2bfloat16(v);
  return *reinterpret_cast<unsigned short*>(&b);
}

static __device__ __forceinline__ h16x2 bch2(unsigned u) {
  return __builtin_bit_cast(h16x2, u);
}

static __device__ __forceinline__ unsigned h2u(h16x2 v) {
  return __builtin_bit_cast(unsigned, v);
}

// ---------------------------------------------------------------------------
// Fused cast + transpose. One pass over f (fp32 [B,T,N,C]):
//   A16[b][t][n][c] = bf16(f)                  (feeds GEMM1)
//   fth[b][h][n][t][48] = fp16(f)              (head-split; one (h, tap)'s
//                                               8r x 48ch = 768 B contiguous)
// ---------------------------------------------------------------------------
__global__ __launch_bounds__(256)
void cast_transpose_kernel(const float* __restrict__ f,
                           __hip_bfloat16* __restrict__ A16,
                           _Float16* __restrict__ fth) {
  const int bn = blockIdx.x;          // b*N + n
  const int n = bn % N_;
  const int b = bn / N_;
#pragma unroll
  for (int i = 0; i < 12; ++i) {      // 12*256 = 3072 = T*C
    int idx = i * 256 + threadIdx.x;  // t*C + c
    int t = idx / C_;
    int c = idx - t * C_;
    int h = c / HD_;
    int c48 = c - h * HD_;
    size_t src = ((size_t)(b * T_ + t) * N_ + n) * C_ + c;
    float v = f[src];
    fth[(((size_t)(b * NH_ + h) * N_ + n) * T_ + t) * HD_ + c48] = (_Float16)v;
    A16[src] = __float2bfloat16(v);
  }
}

// ---------------------------------------------------------------------------
// Pre-transpose weights to [N][K] bf16.
// ---------------------------------------------------------------------------
__global__ __launch_bounds__(256)
void prep_w_kernel(const float* __restrict__ Wq, const float* __restrict__ Woff,
                   const float* __restrict__ Wout,
                   __hip_bfloat16* __restrict__ Wt, __hip_bfloat16* __restrict__ Wot) {
  int nrow = blockIdx.x;           // 0..895
  if (nrow < 512) {
    const float* src; int col, ld;
    if (nrow < 384) { src = Wq; col = nrow; ld = 384; }
    else            { src = Woff; col = nrow - 384; ld = 128; }
    for (int k = threadIdx.x; k < 384; k += 256)
      Wt[(size_t)nrow * 384 + k] = __float2bfloat16(src[(size_t)k * ld + col]);
  } else {
    int col = nrow - 512;
    for (int k = threadIdx.x; k < 384; k += 256)
      Wot[(size_t)col * 384 + k] = __float2bfloat16(Wout[(size_t)k * 384 + col]);
  }
}

// ---------------------------------------------------------------------------
// bf16 MFMA GEMM: acc = A[M,384] @ Wt[N,384]^T + bias, scaled by out0_scale.
// split=1 (GEMM1): N=512; cols<384 -> out0h (fp16, scaled), cols>=384 -> OFFh (fp16).
// split=0 (GEMM2): out0 (fp32).
// ---------------------------------------------------------------------------
__global__ __launch_bounds__(256)
void mfma_gemm_kernel(const __hip_bfloat16* __restrict__ A,
                      const __hip_bfloat16* __restrict__ Wt,
                      const float* __restrict__ b0, const float* __restrict__ b1,
                      float* __restrict__ out0, _Float16* __restrict__ out0h,
                      _Float16* __restrict__ out1,
                      int split, float out0_scale) {
  __shared__ __hip_bfloat16 As[128][40];
  __shared__ __hip_bfloat16 Bs[128][40];
  const int m0 = blockIdx.x * 128;
  const int n0 = blockIdx.y * 128;
  const int tid = threadIdx.x;
  const int wv = tid >> 6, lane = tid & 63;
  const int wr = wv >> 1, wc = wv & 1;
  const int lr = lane & 15, kg = lane >> 4;

  f32x4 acc[4][4] = {};

  for (int k0 = 0; k0 < 384; k0 += 32) {
#pragma unroll
    for (int u = 0; u < 2; ++u) {
      int c = tid + u * 256;
      int row = c >> 2;
      int off = (c & 3) * 8;
      int gm = m0 + row;
      uint4 va = make_uint4(0u, 0u, 0u, 0u);
      if (gm < M_) va = *(const uint4*)(A + (size_t)gm * 384 + k0 + off);
      *(uint4*)&As[row][off] = va;
      uint4 vb = *(const uint4*)(Wt + (size_t)(n0 + row) * 384 + k0 + off);
      *(uint4*)&Bs[row][off] = vb;
    }
    __syncthreads();

    bf16x8 af[4], bfr[4];
#pragma unroll
    for (int i = 0; i < 4; ++i)
      af[i] = *(const bf16x8*)&As[wr * 64 + i * 16 + lr][kg * 8];
#pragma unroll
    for (int i = 0; i < 4; ++i)
      bfr[i] = *(const bf16x8*)&Bs[wc * 64 + i * 16 + lr][kg * 8];

#pragma unroll
    for (int mi = 0; mi < 4; ++mi)
#pragma unroll
      for (int ni = 0; ni < 4; ++ni)
        acc[mi][ni] = __builtin_amdgcn_mfma_f32_16x16x32_bf16(
            af[mi], bfr[ni], acc[mi][ni], 0, 0, 0);
    __syncthreads();
  }

  const int mrow = (lane >> 4) * 4;
#pragma unroll
  for (int mi = 0; mi < 4; ++mi) {
#pragma unroll
    for (int ni = 0; ni < 4; ++ni) {
#pragma unroll
      for (int j = 0; j < 4; ++j) {
        int gm = m0 + wr * 64 + mi * 16 + mrow + j;
        int gn = n0 + wc * 64 + ni * 16 + lr;
        if (gm >= M_) continue;
        float v = acc[mi][ni][j];
        if (!split) {
          out0[(size_t)gm * 384 + gn] = (v + b0[gn]) * out0_scale;
        } else {
          if (gn < 384) out0h[(size_t)gm * 384 + gn] =
              (_Float16)((v + b0[gn]) * out0_scale);
          else          out1[(size_t)gm * 128 + (gn - 384)] =
              (_Float16)(v + b1[gn - 384]);
        }
      }
    }
  }
}

// ---------------------------------------------------------------------------
// Tap precompute:
//   prec_off[row*64+hp] = uint4 of PRE-MULTIPLIED BYTE offsets into fth
//                         (spatial_idx * T*48*2B = idx*768)
//   prec_w  [row*64+hp] = uint2 of fp16{w00,w01}, fp16{w10,w11}
// Tap address in attend becomes base + off + lane*12 (one v_add per tap).
// ---------------------------------------------------------------------------
__global__ __launch_bounds__(256)
void prep_tap_kernel(const _Float16* __restrict__ OFFh,
                     uint4* __restrict__ prec_off, uint2* __restrict__ prec_w) {
  int gid = blockIdx.x * 256 + threadIdx.x;   // row*64 + h*8 + p
  int row = gid >> 6;
  int hp = gid & 63;
  int n = row % N_;
  float cy = (float)(n / HW_);
  float cx = (float)(n % HW_);
  h16x2 off = *(const h16x2*)(OFFh + (size_t)row * 128 + hp * 2);
  float y = cy + (float)off.x;
  float x = cx + (float)off.y;
  float y0f = floorf(y), x0f = floorf(x);
  float wy = y - y0f, wx = x - x0f;
  int y0 = (int)y0f, x0 = (int)x0f;
  int y1 = y0 + 1, x1 = x0 + 1;
  float vy0 = (y0 >= 0 && y0 < HW_) ? 1.f : 0.f;
  float vy1 = (y1 >= 0 && y1 < HW_) ? 1.f : 0.f;
  float vx0 = (x0 >= 0 && x0 < HW_) ? 1.f : 0.f;
  float vx1 = (x1 >= 0 && x1 < HW_) ? 1.f : 0.f;
  int cy0 = min(max(y0, 0), HW_ - 1), cy1 = min(max(y1, 0), HW_ - 1);
  int cx0 = min(max(x0, 0), HW_ - 1), cx1 = min(max(x1, 0), HW_ - 1);
  float w00 = (1.f - wy) * (1.f - wx) * vy0 * vx0;
  float w01 = (1.f - wy) * wx * vy0 * vx1;
  float w10 = wy * (1.f - wx) * vy1 * vx0;
  float w11 = wy * wx * vy1 * vx1;
  uint4 o;
  o.x = (unsigned)(cy0 * HW_ + cx0) * 768u;
  o.y = (unsigned)(cy0 * HW_ + cx1) * 768u;
  o.z = (unsigned)(cy1 * HW_ + cx0) * 768u;
  o.w = (unsigned)(cy1 * HW_ + cx1) * 768u;
  prec_off[gid] = o;
  h16x2 wa = {(_Float16)w00, (_Float16)w01};
  h16x2 wb = {(_Float16)w10, (_Float16)w11};
  prec_w[gid] = make_uint2(h2u(wa), h2u(wb));
}

// ---------------------------------------------------------------------------
// Deformable attention core — coalesced gather + premultiplied tap offsets.
// fth layout [b][h][n][t][48]; lane roles r = lane>>3, k = lane&7;
// p serial with online softmax. Per (t,p): 2 uniform loads (offsets+weights,
// SGPR-able), 4 coalesced 768-B tap bursts at base+off+lane*12 (1 v_add
// each), 12 pk blends, 6 fdot2, 3 shfl, exp, 7 fma.
// ---------------------------------------------------------------------------
__global__ __launch_bounds__(256)
void attend_kernel(const _Float16* __restrict__ fth,
                   const _Float16* __restrict__ Qh,
                   const uint4* __restrict__ prec_off,
                   const uint2* __restrict__ prec_w,
                   __hip_bfloat16* __restrict__ O1) {
  // bijective chunked XCD swizzle over grid of B*N*2 = 5476 blocks
  const int grid = B_ * N_ * 2;
  const int q8 = grid / 8, r8 = grid % 8;
  int c = blockIdx.x & 7, j = blockIdx.x >> 3;
  int id = (c < r8) ? c * (q8 + 1) + j : r8 * (q8 + 1) + (c - r8) * q8 + j;
  const int hq = id & 1;
  const int bn = id >> 1;

  const int n = bn % N_;
  const int b = bn / N_;
  const int w    = threadIdx.x >> 6;
  const int h    = hq * 4 + w;          // one head per wave
  const int lane = threadIdx.x & 63;
  const int r = lane >> 3;              // ref frame
  const int k = lane & 7;               // 6-ch slice

  // head-frame byte base; tap addr = fhb + off_bytes + lane*12
  const char* fhb = (const char*)(fth + (size_t)(b * NH_ + h) * N_ * (T_ * HD_));
  const int laneoff = lane * 12;

  for (int t = 0; t < T_; ++t) {
    const size_t row = (size_t)(b * T_ + t) * N_ + n;

    // q fragment (fp16, pre-scaled by log2e/sqrt(48) in GEMM epilogue)
    uau32x3 qw = *(const uau32x3*)(Qh + row * C_ + h * HD_ + 6 * k);
    h16x2 q01 = bch2(qw.x), q23 = bch2(qw.y), q45 = bch2(qw.z);

    // my r's point-count (mask): p >= npts contributes 0
    int dd = t - r; dd = dd < 0 ? -dd : dd;
    const int npts = max(1, (56 - 8 * dd) / 7);

    const size_t prbase = (size_t)row * 8 + h;
    const uint4* porow = prec_off + prbase * 8;
    const uint2* pwrow = prec_w + prbase * 8;

    float o0 = 0.f, o1 = 0.f, o2 = 0.f, o3 = 0.f, o4 = 0.f, o5 = 0.f;
    float esum = 0.f;

#pragma unroll
    for (int p = 0; p < MP_; ++p) {
      uint4 po = porow[p];               // wave-uniform (SGPR-able)
      uint2 pw = pwrow[p];

      // 4 coalesced tap loads: one v_add each (base + off + lane*12)
      uau32x3 ua = *(const uau32x3*)(fhb + po.x + laneoff);
      uau32x3 ub = *(const uau32x3*)(fhb + po.y + laneoff);
      uau32x3 uc = *(const uau32x3*)(fhb + po.z + laneoff);
      uau32x3 ud = *(const uau32x3*)(fhb + po.w + laneoff);

      h16x2 wa = bch2(pw.x), wb = bch2(pw.y);
      h16x2 tw0h = {wa.x, wa.x}, tw1h = {wa.y, wa.y};
      h16x2 tw2h = {wb.x, wb.x}, tw3h = {wb.y, wb.y};

      // packed fp16 bilinear blend (v_pk_fma_f16)
      h16x2 s01 = bch2(ua.x) * tw0h + bch2(ub.x) * tw1h + bch2(uc.x) * tw2h + bch2(ud.x) * tw3h;
      h16x2 s23 = bch2(ua.y) * tw0h + bch2(ub.y) * tw1h + bch2(uc.y) * tw2h + bch2(ud.y) * tw3h;
      h16x2 s45 = bch2(ua.z) * tw0h + bch2(ub.z) * tw1h + bch2(uc.z) * tw2h + bch2(ud.z) * tw3h;

      // logit partial (v_dot2_f32_f16), then k-reduce (xor 1,2,4)
      float lg = __builtin_amdgcn_fdot2(q01, s01,
                 __builtin_amdgcn_fdot2(q23, s23,
                 __builtin_amdgcn_fdot2(q45, s45, 0.f, false), false), false);
      lg += __shfl_xor(lg, 1);
      lg += __shfl_xor(lg, 2);
      lg += __shfl_xor(lg, 4);

      // online softmax accumulation (no max-sub; masked -> 0)
      float e = (p < npts) ? exp2f(lg) : 0.f;
      esum += e;

      // PV partial: f32 accumulate from fp16 s (v_fma_mix_f32)
      o0 = fmaf((float)s01.x, e, o0);
      o1 = fmaf((float)s01.y, e, o1);
      o2 = fmaf((float)s23.x, e, o2);
      o3 = fmaf((float)s23.y, e, o3);
      o4 = fmaf((float)s45.x, e, o4);
      o5 = fmaf((float)s45.y, e, o5);
    }

    // normalize my r's partial, then reduce over r (xor 8,16,32), fold 1/T
    float inv = __builtin_amdgcn_rcpf(esum);
    o0 *= inv; o1 *= inv; o2 *= inv; o3 *= inv; o4 *= inv; o5 *= inv;

    o0 += __shfl_xor(o0, 8); o0 += __shfl_xor(o0, 16); o0 += __shfl_xor(o0, 32);
    o1 += __shfl_xor(o1, 8); o1 += __shfl_xor(o1, 16); o1 += __shfl_xor(o1, 32);
    o2 += __shfl_xor(o2, 8); o2 += __shfl_xor(o2, 16); o2 += __shfl_xor(o2, 32);
    o3 += __shfl_xor(o3, 8); o3 += __shfl_xor(o3, 16); o3 += __shfl_xor(o3, 32);
    o4 += __shfl_xor(o4, 8); o4 += __shfl_xor(o4, 16); o4 += __shfl_xor(o4, 32);
    o5 += __shfl_xor(o5, 8); o5 += __shfl_xor(o5, 16); o5 += __shfl_xor(o5, 32);

    if (r == 0) {
      __hip_bfloat16* outp = O1 + row * C_ + h * HD_ + 6 * k;
      unsigned* u = (unsigned*)outp;
      u[0] = (unsigned)bf16_bits(o0 * 0.125f) | ((unsigned)bf16_bits(o1 * 0.125f) << 16);
      u[1] = (unsigned)bf16_bits(o2 * 0.125f) | ((unsigned)bf16_bits(o3 * 0.125f) << 16);
      u[2] = (unsigned)bf16_bits(o4 * 0.125f) | ((unsigned)bf16_bits(o5 * 0.125f) << 16);
    }
  }
}

// ---------------------------------------------------------------------------
extern "C" void kernel_launch(void* const* d_in, const int* in_sizes, int n_in,
                              void* d_out, int out_size, void* d_ws, size_t ws_size,
                              hipStream_t stream) {
  const float* f    = (const float*)d_in[0];
  const float* Wq   = (const float*)d_in[1];
  const float* bq   = (const float*)d_in[2];
  const float* Woff = (const float*)d_in[3];
  const float* boff = (const float*)d_in[4];
  const float* Wout = (const float*)d_in[5];
  const float* bout = (const float*)d_in[6];
  float* outp = (float*)d_out;

  // workspace layout (~90 MB):
  //   Qh   fp16 [M,384]        16.8 MB
  //   OFFh fp16 [M,128]         5.6 MB
  //   fth  fp16 [B,H,N,T,48]   16.8 MB
  //   A16  bf16 [M,384]        16.8 MB  (O1 aliases A16 after GEMM1)
  //   Wt / Wot bf16             0.7 MB
  //   prec_off uint4 [M*64]    22.4 MB
  //   prec_w   uint2 [M*64]    11.2 MB
  _Float16* Qh = (_Float16*)d_ws;
  _Float16* OFFh = Qh + (size_t)M_ * C_;
  _Float16* fth = OFFh + (size_t)M_ * 128;
  __hip_bfloat16* A16 = (__hip_bfloat16*)(fth + (size_t)B_ * N_ * T_ * C_);
  __hip_bfloat16* O1  = A16;   // alias: A16 dead after GEMM1, O1 written by attend
  __hip_bfloat16* Wt  = A16 + (size_t)M_ * C_;
  __hip_bfloat16* Wot = Wt + (size_t)512 * 384;
  uint4* prec_off = (uint4*)(Wot + (size_t)384 * 384);
  uint2* prec_w = (uint2*)(prec_off + (size_t)M_ * 64);

  dim3 blk(256);

  cast_transpose_kernel<<<dim3(B_ * N_), blk, 0, stream>>>(f, A16, fth);
  prep_w_kernel<<<dim3(896), blk, 0, stream>>>(Wq, Woff, Wout, Wt, Wot);

  // fused q+off GEMM: [M,384] @ [384,512] -> Qh (fp16, x log2e/sqrt(48)) / OFFh
  mfma_gemm_kernel<<<dim3((M_ + 127) / 128, 4), blk, 0, stream>>>(
      A16, Wt, bq, boff, nullptr, Qh, OFFh, 1, 0.20822825268806912f);

  prep_tap_kernel<<<dim3(M_ / 4), blk, 0, stream>>>(OFFh, prec_off, prec_w);

  attend_kernel<<<dim3(B_ * N_ * 2), blk, 0, stream>>>(fth, Qh, prec_off, prec_w, O1);

  // output GEMM: [M,384] @ [384,384] -> outp
  mfma_gemm_kernel<<<dim3((M_ + 127) / 128, 3), blk, 0, stream>>>(
      O1, Wot, bout, nullptr, outp, nullptr, nullptr, 0, 1.0f);
}

// Round 19
// 280.698 us; speedup vs baseline: 1.1117x; 1.1117x over previous
//
#include <hip/hip_runtime.h>
#include <hip/hip_bf16.h>
#include <hip/hip_fp16.h>
#include <cstddef>

// Problem constants
constexpr int B_  = 2;
constexpr int T_  = 8;
constexpr int HW_ = 37;          // H == W == 37
constexpr int N_  = HW_ * HW_;   // 1369
constexpr int C_  = 384;
constexpr int NH_ = 8;
constexpr int MP_ = 8;
constexpr int HD_ = C_ / NH_;    // 48
constexpr int M_  = B_ * T_ * N_; // 21904

typedef short bf16x8 __attribute__((ext_vector_type(8)));
typedef float f32x4 __attribute__((ext_vector_type(4)));
typedef _Float16 h16x2 __attribute__((ext_vector_type(2)));
typedef unsigned u32x3 __attribute__((ext_vector_type(3)));
typedef u32x3 uau32x3 __attribute__((aligned(4)));

static __device__ __forceinline__ unsigned short bf16_bits(float v) {
  __hip_bfloat16 b = __float2bfloat16(v);
  return *reinterpret_cast<unsigned short*>(&b);
}

static __device__ __forceinline__ h16x2 bch2(unsigned u) {
  return __builtin_bit_cast(h16x2, u);
}

static __device__ __forceinline__ unsigned h2u(h16x2 v) {
  return __builtin_bit_cast(unsigned, v);
}

// ---------------------------------------------------------------------------
// Fused cast + transpose. One pass over f (fp32 [B,T,N,C]):
//   A16[b][t][n][c] = bf16(f)                  (feeds GEMM1)
//   fth[b][h][n][t][48] = fp16(f)              (head-split; one (h, tap)'s
//                                               8r x 48ch = 768 B contiguous)
// ---------------------------------------------------------------------------
__global__ __launch_bounds__(256)
void cast_transpose_kernel(const float* __restrict__ f,
                           __hip_bfloat16* __restrict__ A16,
                           _Float16* __restrict__ fth) {
  const int bn = blockIdx.x;          // b*N + n
  const int n = bn % N_;
  const int b = bn / N_;
#pragma unroll
  for (int i = 0; i < 12; ++i) {      // 12*256 = 3072 = T*C
    int idx = i * 256 + threadIdx.x;  // t*C + c
    int t = idx / C_;
    int c = idx - t * C_;
    int h = c / HD_;
    int c48 = c - h * HD_;
    size_t src = ((size_t)(b * T_ + t) * N_ + n) * C_ + c;
    float v = f[src];
    fth[(((size_t)(b * NH_ + h) * N_ + n) * T_ + t) * HD_ + c48] = (_Float16)v;
    A16[src] = __float2bfloat16(v);
  }
}

// ---------------------------------------------------------------------------
// Pre-transpose weights to [N][K] bf16.
// ---------------------------------------------------------------------------
__global__ __launch_bounds__(256)
void prep_w_kernel(const float* __restrict__ Wq, const float* __restrict__ Woff,
                   const float* __restrict__ Wout,
                   __hip_bfloat16* __restrict__ Wt, __hip_bfloat16* __restrict__ Wot) {
  int nrow = blockIdx.x;           // 0..895
  if (nrow < 512) {
    const float* src; int col, ld;
    if (nrow < 384) { src = Wq; col = nrow; ld = 384; }
    else            { src = Woff; col = nrow - 384; ld = 128; }
    for (int k = threadIdx.x; k < 384; k += 256)
      Wt[(size_t)nrow * 384 + k] = __float2bfloat16(src[(size_t)k * ld + col]);
  } else {
    int col = nrow - 512;
    for (int k = threadIdx.x; k < 384; k += 256)
      Wot[(size_t)col * 384 + k] = __float2bfloat16(Wout[(size_t)k * 384 + col]);
  }
}

// ---------------------------------------------------------------------------
// bf16 MFMA GEMM: acc = A[M,384] @ Wt[N,384]^T + bias, scaled by out0_scale.
// split=1 (GEMM1): N=512; cols<384 -> out0h (fp16, scaled), cols>=384 -> OFFh (fp16).
// split=0 (GEMM2): out0 (fp32).
// ---------------------------------------------------------------------------
__global__ __launch_bounds__(256)
void mfma_gemm_kernel(const __hip_bfloat16* __restrict__ A,
                      const __hip_bfloat16* __restrict__ Wt,
                      const float* __restrict__ b0, const float* __restrict__ b1,
                      float* __restrict__ out0, _Float16* __restrict__ out0h,
                      _Float16* __restrict__ out1,
                      int split, float out0_scale) {
  __shared__ __hip_bfloat16 As[128][40];
  __shared__ __hip_bfloat16 Bs[128][40];
  const int m0 = blockIdx.x * 128;
  const int n0 = blockIdx.y * 128;
  const int tid = threadIdx.x;
  const int wv = tid >> 6, lane = tid & 63;
  const int wr = wv >> 1, wc = wv & 1;
  const int lr = lane & 15, kg = lane >> 4;

  f32x4 acc[4][4] = {};

  for (int k0 = 0; k0 < 384; k0 += 32) {
#pragma unroll
    for (int u = 0; u < 2; ++u) {
      int c = tid + u * 256;
      int row = c >> 2;
      int off = (c & 3) * 8;
      int gm = m0 + row;
      uint4 va = make_uint4(0u, 0u, 0u, 0u);
      if (gm < M_) va = *(const uint4*)(A + (size_t)gm * 384 + k0 + off);
      *(uint4*)&As[row][off] = va;
      uint4 vb = *(const uint4*)(Wt + (size_t)(n0 + row) * 384 + k0 + off);
      *(uint4*)&Bs[row][off] = vb;
    }
    __syncthreads();

    bf16x8 af[4], bfr[4];
#pragma unroll
    for (int i = 0; i < 4; ++i)
      af[i] = *(const bf16x8*)&As[wr * 64 + i * 16 + lr][kg * 8];
#pragma unroll
    for (int i = 0; i < 4; ++i)
      bfr[i] = *(const bf16x8*)&Bs[wc * 64 + i * 16 + lr][kg * 8];

#pragma unroll
    for (int mi = 0; mi < 4; ++mi)
#pragma unroll
      for (int ni = 0; ni < 4; ++ni)
        acc[mi][ni] = __builtin_amdgcn_mfma_f32_16x16x32_bf16(
            af[mi], bfr[ni], acc[mi][ni], 0, 0, 0);
    __syncthreads();
  }

  const int mrow = (lane >> 4) * 4;
#pragma unroll
  for (int mi = 0; mi < 4; ++mi) {
#pragma unroll
    for (int ni = 0; ni < 4; ++ni) {
#pragma unroll
      for (int j = 0; j < 4; ++j) {
        int gm = m0 + wr * 64 + mi * 16 + mrow + j;
        int gn = n0 + wc * 64 + ni * 16 + lr;
        if (gm >= M_) continue;
        float v = acc[mi][ni][j];
        if (!split) {
          out0[(size_t)gm * 384 + gn] = (v + b0[gn]) * out0_scale;
        } else {
          if (gn < 384) out0h[(size_t)gm * 384 + gn] =
              (_Float16)((v + b0[gn]) * out0_scale);
          else          out1[(size_t)gm * 128 + (gn - 384)] =
              (_Float16)(v + b1[gn - 384]);
        }
      }
    }
  }
}

// ---------------------------------------------------------------------------
// Tap precompute: for each (row, h, p) emit 16 B:
//   .x = i00 | i01<<16   .y = i10 | i11<<16   (clamped u16 spatial indices)
//   .z = fp16{w00,w01}   .w = fp16{w10,w11}   (border-masked bilinear weights)
// ---------------------------------------------------------------------------
__global__ __launch_bounds__(256)
void prep_tap_kernel(const _Float16* __restrict__ OFFh, uint4* __restrict__ prec) {
  int gid = blockIdx.x * 256 + threadIdx.x;   // row*64 + h*8 + p
  int row = gid >> 6;
  int hp = gid & 63;
  int n = row % N_;
  float cy = (float)(n / HW_);
  float cx = (float)(n % HW_);
  h16x2 off = *(const h16x2*)(OFFh + (size_t)row * 128 + hp * 2);
  float y = cy + (float)off.x;
  float x = cx + (float)off.y;
  float y0f = floorf(y), x0f = floorf(x);
  float wy = y - y0f, wx = x - x0f;
  int y0 = (int)y0f, x0 = (int)x0f;
  int y1 = y0 + 1, x1 = x0 + 1;
  float vy0 = (y0 >= 0 && y0 < HW_) ? 1.f : 0.f;
  float vy1 = (y1 >= 0 && y1 < HW_) ? 1.f : 0.f;
  float vx0 = (x0 >= 0 && x0 < HW_) ? 1.f : 0.f;
  float vx1 = (x1 >= 0 && x1 < HW_) ? 1.f : 0.f;
  int cy0 = min(max(y0, 0), HW_ - 1), cy1 = min(max(y1, 0), HW_ - 1);
  int cx0 = min(max(x0, 0), HW_ - 1), cx1 = min(max(x1, 0), HW_ - 1);
  float w00 = (1.f - wy) * (1.f - wx) * vy0 * vx0;
  float w01 = (1.f - wy) * wx * vy0 * vx1;
  float w10 = wy * (1.f - wx) * vy1 * vx0;
  float w11 = wy * wx * vy1 * vx1;
  uint4 o;
  o.x = (unsigned)(cy0 * HW_ + cx0) | ((unsigned)(cy0 * HW_ + cx1) << 16);
  o.y = (unsigned)(cy1 * HW_ + cx0) | ((unsigned)(cy1 * HW_ + cx1) << 16);
  h16x2 wa = {(_Float16)w00, (_Float16)w01};
  h16x2 wb = {(_Float16)w10, (_Float16)w11};
  o.z = h2u(wa);
  o.w = h2u(wb);
  prec[gid] = o;
}

// ---------------------------------------------------------------------------
// Deformable attention core — round-16 body, T-SPLIT GRID for occupancy.
// Grid = B*N*2*T = 43808 blocks (id = bn*16 + hq*8 + t, bn-major so the
// chunked XCD swizzle keeps each XCD on a contiguous bn range; fth slice
// per XCD ~2MB < 4MB L2). 4 waves/block, one head per wave, ONE t per block.
// fth layout [b][h][n][t][48]; lane roles r = lane>>3, k = lane&7;
// p serial with online softmax.
// ---------------------------------------------------------------------------
__global__ __launch_bounds__(256)
void attend_kernel(const _Float16* __restrict__ fth,
                   const _Float16* __restrict__ Qh,
                   const uint4* __restrict__ prec,
                   __hip_bfloat16* __restrict__ O1) {
  // bijective chunked XCD swizzle over grid of B*N*2*T = 43808 blocks
  const int grid = B_ * N_ * 2 * T_;
  const int q8 = grid / 8;                 // divisible by 8
  int cxd = blockIdx.x & 7, jj = blockIdx.x >> 3;
  int id = cxd * q8 + jj;
  const int t  = id & 7;
  const int hq = (id >> 3) & 1;
  const int bn = id >> 4;

  const int n = bn % N_;
  const int b = bn / N_;
  const int w    = threadIdx.x >> 6;
  const int h    = hq * 4 + w;          // one head per wave
  const int lane = threadIdx.x & 63;
  const int r = lane >> 3;              // ref frame
  const int k = lane & 7;               // 6-ch slice

  // head-frame base: tap tile = 384 elems (768 B)
  const _Float16* fh = fth + (size_t)(b * NH_ + h) * N_ * (T_ * HD_);
  const int laneoff = lane * 6;

  const size_t row = (size_t)(b * T_ + t) * N_ + n;

  // q fragment (fp16, pre-scaled by log2e/sqrt(48) in GEMM epilogue)
  uau32x3 qw = *(const uau32x3*)(Qh + row * C_ + h * HD_ + 6 * k);
  h16x2 q01 = bch2(qw.x), q23 = bch2(qw.y), q45 = bch2(qw.z);

  // my r's point-count (mask): p >= npts contributes 0
  int dd = t - r; dd = dd < 0 ? -dd : dd;
  const int npts = max(1, (56 - 8 * dd) / 7);

  const uint4* precrow = prec + ((size_t)row * 8 + h) * 8;

  float o0 = 0.f, o1 = 0.f, o2 = 0.f, o3 = 0.f, o4 = 0.f, o5 = 0.f;
  float esum = 0.f;

#pragma unroll
  for (int p = 0; p < MP_; ++p) {
    uint4 pr = precrow[p];             // uniform 16-B load (broadcast)
    int i00 = pr.x & 0xffff, i01 = pr.x >> 16;
    int i10 = pr.y & 0xffff, i11 = pr.y >> 16;
    h16x2 wa = bch2(pr.z), wb = bch2(pr.w);
    h16x2 tw0h = {wa.x, wa.x}, tw1h = {wa.y, wa.y};
    h16x2 tw2h = {wb.x, wb.x}, tw3h = {wb.y, wb.y};

    // 4 coalesced tap loads: base + lane*12B, 768-B wave burst each
    uau32x3 ua = *(const uau32x3*)(fh + i00 * (T_ * HD_) + laneoff);
    uau32x3 ub = *(const uau32x3*)(fh + i01 * (T_ * HD_) + laneoff);
    uau32x3 uc = *(const uau32x3*)(fh + i10 * (T_ * HD_) + laneoff);
    uau32x3 ud = *(const uau32x3*)(fh + i11 * (T_ * HD_) + laneoff);

    // packed fp16 bilinear blend (v_pk_fma_f16)
    h16x2 s01 = bch2(ua.x) * tw0h + bch2(ub.x) * tw1h + bch2(uc.x) * tw2h + bch2(ud.x) * tw3h;
    h16x2 s23 = bch2(ua.y) * tw0h + bch2(ub.y) * tw1h + bch2(uc.y) * tw2h + bch2(ud.y) * tw3h;
    h16x2 s45 = bch2(ua.z) * tw0h + bch2(ub.z) * tw1h + bch2(uc.z) * tw2h + bch2(ud.z) * tw3h;

    // logit partial (v_dot2_f32_f16), then k-reduce (xor 1,2,4)
    float lg = __builtin_amdgcn_fdot2(q01, s01,
               __builtin_amdgcn_fdot2(q23, s23,
               __builtin_amdgcn_fdot2(q45, s45, 0.f, false), false), false);
    lg += __shfl_xor(lg, 1);
    lg += __shfl_xor(lg, 2);
    lg += __shfl_xor(lg, 4);

    // online softmax accumulation (no max-sub; masked -> 0)
    float e = (p < npts) ? exp2f(lg) : 0.f;
    esum += e;

    // PV partial: f32 accumulate from fp16 s (v_fma_mix_f32)
    o0 = fmaf((float)s01.x, e, o0);
    o1 = fmaf((float)s01.y, e, o1);
    o2 = fmaf((float)s23.x, e, o2);
    o3 = fmaf((float)s23.y, e, o3);
    o4 = fmaf((float)s45.x, e, o4);
    o5 = fmaf((float)s45.y, e, o5);
  }

  // normalize my r's partial, then reduce over r (xor 8,16,32), fold 1/T
  float inv = __builtin_amdgcn_rcpf(esum);
  o0 *= inv; o1 *= inv; o2 *= inv; o3 *= inv; o4 *= inv; o5 *= inv;

  o0 += __shfl_xor(o0, 8); o0 += __shfl_xor(o0, 16); o0 += __shfl_xor(o0, 32);
  o1 += __shfl_xor(o1, 8); o1 += __shfl_xor(o1, 16); o1 += __shfl_xor(o1, 32);
  o2 += __shfl_xor(o2, 8); o2 += __shfl_xor(o2, 16); o2 += __shfl_xor(o2, 32);
  o3 += __shfl_xor(o3, 8); o3 += __shfl_xor(o3, 16); o3 += __shfl_xor(o3, 32);
  o4 += __shfl_xor(o4, 8); o4 += __shfl_xor(o4, 16); o4 += __shfl_xor(o4, 32);
  o5 += __shfl_xor(o5, 8); o5 += __shfl_xor(o5, 16); o5 += __shfl_xor(o5, 32);

  if (r == 0) {
    __hip_bfloat16* outp = O1 + row * C_ + h * HD_ + 6 * k;
    unsigned* u = (unsigned*)outp;
    u[0] = (unsigned)bf16_bits(o0 * 0.125f) | ((unsigned)bf16_bits(o1 * 0.125f) << 16);
    u[1] = (unsigned)bf16_bits(o2 * 0.125f) | ((unsigned)bf16_bits(o3 * 0.125f) << 16);
    u[2] = (unsigned)bf16_bits(o4 * 0.125f) | ((unsigned)bf16_bits(o5 * 0.125f) << 16);
  }
}

// ---------------------------------------------------------------------------
extern "C" void kernel_launch(void* const* d_in, const int* in_sizes, int n_in,
                              void* d_out, int out_size, void* d_ws, size_t ws_size,
                              hipStream_t stream) {
  const float* f    = (const float*)d_in[0];
  const float* Wq   = (const float*)d_in[1];
  const float* bq   = (const float*)d_in[2];
  const float* Woff = (const float*)d_in[3];
  const float* boff = (const float*)d_in[4];
  const float* Wout = (const float*)d_in[5];
  const float* bout = (const float*)d_in[6];
  float* outp = (float*)d_out;

  // workspace layout (~79 MB):
  //   Qh   fp16 [M,384]        16.8 MB
  //   OFFh fp16 [M,128]         5.6 MB
  //   fth  fp16 [B,H,N,T,48]   16.8 MB
  //   A16  bf16 [M,384]        16.8 MB  (O1 aliases A16 after GEMM1)
  //   Wt / Wot bf16             0.7 MB
  //   prec uint4 [M*64]        22.4 MB
  _Float16* Qh = (_Float16*)d_ws;
  _Float16* OFFh = Qh + (size_t)M_ * C_;
  _Float16* fth = OFFh + (size_t)M_ * 128;
  __hip_bfloat16* A16 = (__hip_bfloat16*)(fth + (size_t)B_ * N_ * T_ * C_);
  __hip_bfloat16* O1  = A16;   // alias: A16 dead after GEMM1, O1 written by attend
  __hip_bfloat16* Wt  = A16 + (size_t)M_ * C_;
  __hip_bfloat16* Wot = Wt + (size_t)512 * 384;
  uint4* prec = (uint4*)(Wot + (size_t)384 * 384);

  dim3 blk(256);

  cast_transpose_kernel<<<dim3(B_ * N_), blk, 0, stream>>>(f, A16, fth);
  prep_w_kernel<<<dim3(896), blk, 0, stream>>>(Wq, Woff, Wout, Wt, Wot);

  // fused q+off GEMM: [M,384] @ [384,512] -> Qh (fp16, x log2e/sqrt(48)) / OFFh
  mfma_gemm_kernel<<<dim3((M_ + 127) / 128, 4), blk, 0, stream>>>(
      A16, Wt, bq, boff, nullptr, Qh, OFFh, 1, 0.20822825268806912f);

  prep_tap_kernel<<<dim3(M_ / 4), blk, 0, stream>>>(OFFh, prec);

  attend_kernel<<<dim3(B_ * N_ * 2 * T_), blk, 0, stream>>>(fth, Qh, prec, O1);

  // output GEMM: [M,384] @ [384,384] -> outp
  mfma_gemm_kernel<<<dim3((M_ + 127) / 128, 3), blk, 0, stream>>>(
      O1, Wot, bout, nullptr, outp, nullptr, nullptr, 0, 1.0f);
}

// Round 20
// 279.582 us; speedup vs baseline: 1.1161x; 1.0040x over previous
//
#include <hip/hip_runtime.h>
#include <hip/hip_bf16.h>
#include <hip/hip_fp16.h>
#include <cstddef>

// Problem constants
constexpr int B_  = 2;
constexpr int T_  = 8;
constexpr int HW_ = 37;          // H == W == 37
constexpr int N_  = HW_ * HW_;   // 1369
constexpr int C_  = 384;
constexpr int NH_ = 8;
constexpr int MP_ = 8;
constexpr int HD_ = C_ / NH_;    // 48
constexpr int M_  = B_ * T_ * N_; // 21904

typedef short bf16x8 __attribute__((ext_vector_type(8)));
typedef float f32x4 __attribute__((ext_vector_type(4)));
typedef _Float16 h16x2 __attribute__((ext_vector_type(2)));
typedef unsigned u32x3 __attribute__((ext_vector_type(3)));
typedef u32x3 uau32x3 __attribute__((aligned(4)));

static __device__ __forceinline__ unsigned short bf16_bits(float v) {
  __hip_bfloat16 b = __float2bfloat16(v);
  return *reinterpret_cast<unsigned short*>(&b);
}

static __device__ __forceinline__ h16x2 bch2(unsigned u) {
  return __builtin_bit_cast(h16x2, u);
}

static __device__ __forceinline__ unsigned h2u(h16x2 v) {
  return __builtin_bit_cast(unsigned, v);
}

// packed fp16 shuffle-add: one 32-bit shuffle moves two halves
static __device__ __forceinline__ h16x2 pk_shfl_add(h16x2 v, int mask) {
  unsigned u = h2u(v);
  unsigned w = __shfl_xor(u, mask);
  return v + bch2(w);
}

// ---------------------------------------------------------------------------
// Fused cast + transpose. One pass over f (fp32 [B,T,N,C]):
//   A16[b][t][n][c] = bf16(f)                  (feeds GEMM1)
//   fth[b][h][n][t][48] = fp16(f)              (head-split; one (h, tap)'s
//                                               8r x 48ch = 768 B contiguous)
// ---------------------------------------------------------------------------
__global__ __launch_bounds__(256)
void cast_transpose_kernel(const float* __restrict__ f,
                           __hip_bfloat16* __restrict__ A16,
                           _Float16* __restrict__ fth) {
  const int bn = blockIdx.x;          // b*N + n
  const int n = bn % N_;
  const int b = bn / N_;
#pragma unroll
  for (int i = 0; i < 12; ++i) {      // 12*256 = 3072 = T*C
    int idx = i * 256 + threadIdx.x;  // t*C + c
    int t = idx / C_;
    int c = idx - t * C_;
    int h = c / HD_;
    int c48 = c - h * HD_;
    size_t src = ((size_t)(b * T_ + t) * N_ + n) * C_ + c;
    float v = f[src];
    fth[(((size_t)(b * NH_ + h) * N_ + n) * T_ + t) * HD_ + c48] = (_Float16)v;
    A16[src] = __float2bfloat16(v);
  }
}

// ---------------------------------------------------------------------------
// Pre-transpose weights to [N][K] bf16.
// ---------------------------------------------------------------------------
__global__ __launch_bounds__(256)
void prep_w_kernel(const float* __restrict__ Wq, const float* __restrict__ Woff,
                   const float* __restrict__ Wout,
                   __hip_bfloat16* __restrict__ Wt, __hip_bfloat16* __restrict__ Wot) {
  int nrow = blockIdx.x;           // 0..895
  if (nrow < 512) {
    const float* src; int col, ld;
    if (nrow < 384) { src = Wq; col = nrow; ld = 384; }
    else            { src = Woff; col = nrow - 384; ld = 128; }
    for (int k = threadIdx.x; k < 384; k += 256)
      Wt[(size_t)nrow * 384 + k] = __float2bfloat16(src[(size_t)k * ld + col]);
  } else {
    int col = nrow - 512;
    for (int k = threadIdx.x; k < 384; k += 256)
      Wot[(size_t)col * 384 + k] = __float2bfloat16(Wout[(size_t)k * 384 + col]);
  }
}

// ---------------------------------------------------------------------------
// bf16 MFMA GEMM: acc = A[M,384] @ Wt[N,384]^T + bias, scaled by out0_scale.
// split=1 (GEMM1): N=512; cols<384 -> out0h (fp16, scaled), cols>=384 -> OFFh (fp16).
// split=0 (GEMM2): out0 (fp32).
// ---------------------------------------------------------------------------
__global__ __launch_bounds__(256)
void mfma_gemm_kernel(const __hip_bfloat16* __restrict__ A,
                      const __hip_bfloat16* __restrict__ Wt,
                      const float* __restrict__ b0, const float* __restrict__ b1,
                      float* __restrict__ out0, _Float16* __restrict__ out0h,
                      _Float16* __restrict__ out1,
                      int split, float out0_scale) {
  __shared__ __hip_bfloat16 As[128][40];
  __shared__ __hip_bfloat16 Bs[128][40];
  const int m0 = blockIdx.x * 128;
  const int n0 = blockIdx.y * 128;
  const int tid = threadIdx.x;
  const int wv = tid >> 6, lane = tid & 63;
  const int wr = wv >> 1, wc = wv & 1;
  const int lr = lane & 15, kg = lane >> 4;

  f32x4 acc[4][4] = {};

  for (int k0 = 0; k0 < 384; k0 += 32) {
#pragma unroll
    for (int u = 0; u < 2; ++u) {
      int c = tid + u * 256;
      int row = c >> 2;
      int off = (c & 3) * 8;
      int gm = m0 + row;
      uint4 va = make_uint4(0u, 0u, 0u, 0u);
      if (gm < M_) va = *(const uint4*)(A + (size_t)gm * 384 + k0 + off);
      *(uint4*)&As[row][off] = va;
      uint4 vb = *(const uint4*)(Wt + (size_t)(n0 + row) * 384 + k0 + off);
      *(uint4*)&Bs[row][off] = vb;
    }
    __syncthreads();

    bf16x8 af[4], bfr[4];
#pragma unroll
    for (int i = 0; i < 4; ++i)
      af[i] = *(const bf16x8*)&As[wr * 64 + i * 16 + lr][kg * 8];
#pragma unroll
    for (int i = 0; i < 4; ++i)
      bfr[i] = *(const bf16x8*)&Bs[wc * 64 + i * 16 + lr][kg * 8];

#pragma unroll
    for (int mi = 0; mi < 4; ++mi)
#pragma unroll
      for (int ni = 0; ni < 4; ++ni)
        acc[mi][ni] = __builtin_amdgcn_mfma_f32_16x16x32_bf16(
            af[mi], bfr[ni], acc[mi][ni], 0, 0, 0);
    __syncthreads();
  }

  const int mrow = (lane >> 4) * 4;
#pragma unroll
  for (int mi = 0; mi < 4; ++mi) {
#pragma unroll
    for (int ni = 0; ni < 4; ++ni) {
#pragma unroll
      for (int j = 0; j < 4; ++j) {
        int gm = m0 + wr * 64 + mi * 16 + mrow + j;
        int gn = n0 + wc * 64 + ni * 16 + lr;
        if (gm >= M_) continue;
        float v = acc[mi][ni][j];
        if (!split) {
          out0[(size_t)gm * 384 + gn] = (v + b0[gn]) * out0_scale;
        } else {
          if (gn < 384) out0h[(size_t)gm * 384 + gn] =
              (_Float16)((v + b0[gn]) * out0_scale);
          else          out1[(size_t)gm * 128 + (gn - 384)] =
              (_Float16)(v + b1[gn - 384]);
        }
      }
    }
  }
}

// ---------------------------------------------------------------------------
// Tap precompute: for each (row, h, p) emit 16 B:
//   .x = i00 | i01<<16   .y = i10 | i11<<16   (clamped u16 spatial indices)
//   .z = fp16{w00,w01}   .w = fp16{w10,w11}   (border-masked bilinear weights)
// ---------------------------------------------------------------------------
__global__ __launch_bounds__(256)
void prep_tap_kernel(const _Float16* __restrict__ OFFh, uint4* __restrict__ prec) {
  int gid = blockIdx.x * 256 + threadIdx.x;   // row*64 + h*8 + p
  int row = gid >> 6;
  int hp = gid & 63;
  int n = row % N_;
  float cy = (float)(n / HW_);
  float cx = (float)(n % HW_);
  h16x2 off = *(const h16x2*)(OFFh + (size_t)row * 128 + hp * 2);
  float y = cy + (float)off.x;
  float x = cx + (float)off.y;
  float y0f = floorf(y), x0f = floorf(x);
  float wy = y - y0f, wx = x - x0f;
  int y0 = (int)y0f, x0 = (int)x0f;
  int y1 = y0 + 1, x1 = x0 + 1;
  float vy0 = (y0 >= 0 && y0 < HW_) ? 1.f : 0.f;
  float vy1 = (y1 >= 0 && y1 < HW_) ? 1.f : 0.f;
  float vx0 = (x0 >= 0 && x0 < HW_) ? 1.f : 0.f;
  float vx1 = (x1 >= 0 && x1 < HW_) ? 1.f : 0.f;
  int cy0 = min(max(y0, 0), HW_ - 1), cy1 = min(max(y1, 0), HW_ - 1);
  int cx0 = min(max(x0, 0), HW_ - 1), cx1 = min(max(x1, 0), HW_ - 1);
  float w00 = (1.f - wy) * (1.f - wx) * vy0 * vx0;
  float w01 = (1.f - wy) * wx * vy0 * vx1;
  float w10 = wy * (1.f - wx) * vy1 * vx0;
  float w11 = wy * wx * vy1 * vx1;
  uint4 o;
  o.x = (unsigned)(cy0 * HW_ + cx0) | ((unsigned)(cy0 * HW_ + cx1) << 16);
  o.y = (unsigned)(cy1 * HW_ + cx0) | ((unsigned)(cy1 * HW_ + cx1) << 16);
  h16x2 wa = {(_Float16)w00, (_Float16)w01};
  h16x2 wb = {(_Float16)w10, (_Float16)w11};
  o.z = h2u(wa);
  o.w = h2u(wb);
  prec[gid] = o;
}

// ---------------------------------------------------------------------------
// Deformable attention core — T-split grid + PACKED-FP16 PV/epilogue.
// Grid = B*N*2*T = 43808 blocks (bn-major under chunked XCD swizzle).
// 4 waves/block, one head per wave, one t per block.
// Lane roles r = lane>>3, k = lane&7; p serial with online softmax.
// PV accumulates packed fp16 with e scaled by 1/16 (overflow guard);
// per-r normalize folds x16 and 1/T (scale = 2*rcp); r-reduce = 9 packed
// shuffles (was 18 f32).
// ---------------------------------------------------------------------------
__global__ __launch_bounds__(256)
void attend_kernel(const _Float16* __restrict__ fth,
                   const _Float16* __restrict__ Qh,
                   const uint4* __restrict__ prec,
                   __hip_bfloat16* __restrict__ O1) {
  // bijective chunked XCD swizzle over grid of B*N*2*T = 43808 blocks
  const int grid = B_ * T_ * N_ * 2;
  const int q8 = grid / 8;                 // divisible by 8
  int cxd = blockIdx.x & 7, jj = blockIdx.x >> 3;
  int id = cxd * q8 + jj;
  const int t  = id & 7;
  const int hq = (id >> 3) & 1;
  const int bn = id >> 4;

  const int n = bn % N_;
  const int b = bn / N_;
  const int w    = threadIdx.x >> 6;
  const int h    = hq * 4 + w;          // one head per wave
  const int lane = threadIdx.x & 63;
  const int r = lane >> 3;              // ref frame
  const int k = lane & 7;               // 6-ch slice

  // head-frame base: tap tile = 384 elems (768 B)
  const _Float16* fh = fth + (size_t)(b * NH_ + h) * N_ * (T_ * HD_);
  const int laneoff = lane * 6;

  const size_t row = (size_t)(b * T_ + t) * N_ + n;

  // q fragment (fp16, pre-scaled by log2e/sqrt(48) in GEMM epilogue)
  uau32x3 qw = *(const uau32x3*)(Qh + row * C_ + h * HD_ + 6 * k);
  h16x2 q01 = bch2(qw.x), q23 = bch2(qw.y), q45 = bch2(qw.z);

  // my r's point-count (mask): p >= npts contributes 0
  int dd = t - r; dd = dd < 0 ? -dd : dd;
  const int npts = max(1, (56 - 8 * dd) / 7);

  const uint4* precrow = prec + ((size_t)row * 8 + h) * 8;

  h16x2 o01 = {(_Float16)0.f, (_Float16)0.f}, o23 = o01, o45 = o01;
  float esum = 0.f;

#pragma unroll
  for (int p = 0; p < MP_; ++p) {
    uint4 pr = precrow[p];             // uniform 16-B load (broadcast)
    int i00 = pr.x & 0xffff, i01 = pr.x >> 16;
    int i10 = pr.y & 0xffff, i11 = pr.y >> 16;
    h16x2 wa = bch2(pr.z), wb = bch2(pr.w);
    h16x2 tw0h = {wa.x, wa.x}, tw1h = {wa.y, wa.y};
    h16x2 tw2h = {wb.x, wb.x}, tw3h = {wb.y, wb.y};

    // 4 coalesced tap loads: base + lane*12B, 768-B wave burst each
    uau32x3 ua = *(const uau32x3*)(fh + i00 * (T_ * HD_) + laneoff);
    uau32x3 ub = *(const uau32x3*)(fh + i01 * (T_ * HD_) + laneoff);
    uau32x3 uc = *(const uau32x3*)(fh + i10 * (T_ * HD_) + laneoff);
    uau32x3 ud = *(const uau32x3*)(fh + i11 * (T_ * HD_) + laneoff);

    // packed fp16 bilinear blend (v_pk_fma_f16)
    h16x2 s01 = bch2(ua.x) * tw0h + bch2(ub.x) * tw1h + bch2(uc.x) * tw2h + bch2(ud.x) * tw3h;
    h16x2 s23 = bch2(ua.y) * tw0h + bch2(ub.y) * tw1h + bch2(uc.y) * tw2h + bch2(ud.y) * tw3h;
    h16x2 s45 = bch2(ua.z) * tw0h + bch2(ub.z) * tw1h + bch2(uc.z) * tw2h + bch2(ud.z) * tw3h;

    // logit partial (v_dot2_f32_f16), then k-reduce (xor 1,2,4)
    float lg = __builtin_amdgcn_fdot2(q01, s01,
               __builtin_amdgcn_fdot2(q23, s23,
               __builtin_amdgcn_fdot2(q45, s45, 0.f, false), false), false);
    lg += __shfl_xor(lg, 1);
    lg += __shfl_xor(lg, 2);
    lg += __shfl_xor(lg, 4);

    // online softmax accumulation (no max-sub; masked -> 0)
    float e = (p < npts) ? exp2f(lg) : 0.f;
    esum += e;

    // PV partial: packed fp16, e scaled by 1/16 (undone in normalize)
    _Float16 eh = (_Float16)(e * 0.0625f);
    h16x2 ev = {eh, eh};
    o01 += ev * s01;
    o23 += ev * s23;
    o45 += ev * s45;
  }

  // normalize my r's partial: scale = 16 * (1/T) * rcp(esum) = 2*rcp(esum)
  float sc = 2.0f * __builtin_amdgcn_rcpf(esum);
  _Float16 sch = (_Float16)sc;
  h16x2 scv = {sch, sch};
  o01 *= scv; o23 *= scv; o45 *= scv;

  // r-reduce: 9 packed shuffles (xor 8,16,32 over 3 packed regs)
#pragma unroll
  for (int m = 8; m <= 32; m <<= 1) {
    o01 = pk_shfl_add(o01, m);
    o23 = pk_shfl_add(o23, m);
    o45 = pk_shfl_add(o45, m);
  }

  if (r == 0) {
    __hip_bfloat16* outp = O1 + row * C_ + h * HD_ + 6 * k;
    unsigned* u = (unsigned*)outp;
    u[0] = (unsigned)bf16_bits((float)o01.x) | ((unsigned)bf16_bits((float)o01.y) << 16);
    u[1] = (unsigned)bf16_bits((float)o23.x) | ((unsigned)bf16_bits((float)o23.y) << 16);
    u[2] = (unsigned)bf16_bits((float)o45.x) | ((unsigned)bf16_bits((float)o45.y) << 16);
  }
}

// ---------------------------------------------------------------------------
extern "C" void kernel_launch(void* const* d_in, const int* in_sizes, int n_in,
                              void* d_out, int out_size, void* d_ws, size_t ws_size,
                              hipStream_t stream) {
  const float* f    = (const float*)d_in[0];
  const float* Wq   = (const float*)d_in[1];
  const float* bq   = (const float*)d_in[2];
  const float* Woff = (const float*)d_in[3];
  const float* boff = (const float*)d_in[4];
  const float* Wout = (const float*)d_in[5];
  const float* bout = (const float*)d_in[6];
  float* outp = (float*)d_out;

  // workspace layout (~79 MB):
  //   Qh   fp16 [M,384]        16.8 MB
  //   OFFh fp16 [M,128]         5.6 MB
  //   fth  fp16 [B,H,N,T,48]   16.8 MB
  //   A16  bf16 [M,384]        16.8 MB  (O1 aliases A16 after GEMM1)
  //   Wt / Wot bf16             0.7 MB
  //   prec uint4 [M*64]        22.4 MB
  _Float16* Qh = (_Float16*)d_ws;
  _Float16* OFFh = Qh + (size_t)M_ * C_;
  _Float16* fth = OFFh + (size_t)M_ * 128;
  __hip_bfloat16* A16 = (__hip_bfloat16*)(fth + (size_t)B_ * N_ * T_ * C_);
  __hip_bfloat16* O1  = A16;   // alias: A16 dead after GEMM1, O1 written by attend
  __hip_bfloat16* Wt  = A16 + (size_t)M_ * C_;
  __hip_bfloat16* Wot = Wt + (size_t)512 * 384;
  uint4* prec = (uint4*)(Wot + (size_t)384 * 384);

  dim3 blk(256);

  cast_transpose_kernel<<<dim3(B_ * N_), blk, 0, stream>>>(f, A16, fth);
  prep_w_kernel<<<dim3(896), blk, 0, stream>>>(Wq, Woff, Wout, Wt, Wot);

  // fused q+off GEMM: [M,384] @ [384,512] -> Qh (fp16, x log2e/sqrt(48)) / OFFh
  mfma_gemm_kernel<<<dim3((M_ + 127) / 128, 4), blk, 0, stream>>>(
      A16, Wt, bq, boff, nullptr, Qh, OFFh, 1, 0.20822825268806912f);

  prep_tap_kernel<<<dim3(M_ / 4), blk, 0, stream>>>(OFFh, prec);

  attend_kernel<<<dim3(B_ * N_ * 2 * T_), blk, 0, stream>>>(fth, Qh, prec, O1);

  // output GEMM: [M,384] @ [384,384] -> outp
  mfma_gemm_kernel<<<dim3((M_ + 127) / 128, 3), blk, 0, stream>>>(
      O1, Wot, bout, nullptr, outp, nullptr, nullptr, 0, 1.0f);
}